// Round 13
// baseline (312.982 us; speedup 1.0000x reference)
//
#include <hip/hip_runtime.h>
#include <hip/hip_bf16.h>

#define B_SZ     32
#define IN_DIM   1024
#define K_TOTAL  525824          // 1024 linear + 524800 triu = 4108 * 128
#define OUT_DIM  512
#define NCH      4108            // 128-k chunks
#define KGN      128             // k-segment groups (chunk stride)
#define F_BYTES  ((size_t)NCH * 8192)            // 33,652,736 packed bf16 features
#define P_ELEMS  ((size_t)KGN * B_SZ * OUT_DIM)  // 128 * 16384 partials
#define NEED_WS  (F_BYTES + P_ELEMS * 4)

typedef __attribute__((ext_vector_type(8))) short bfrag;   // 8 bf16 = 4 VGPR
typedef __attribute__((ext_vector_type(4))) float f32x4;

// async global->LDS, 16B per lane; LDS dest = wave-uniform base + lane*16
#define GLD16(g, l) __builtin_amdgcn_global_load_lds(                      \
    (const __attribute__((address_space(1))) void*)(g),                    \
    (__attribute__((address_space(3))) void*)(l), 16, 0, 0)

// fp32 -> bf16 round-to-nearest-even (pure integer)
__device__ inline unsigned bf16r(float f)
{
    unsigned u = __builtin_bit_cast(unsigned, f);
    return (u + 0x7FFFu + ((u >> 16) & 1u)) >> 16;
}
__device__ inline unsigned pk2(float a, float b)
{
    return bf16r(a) | (bf16r(b) << 16);
}

// ---------------------------------------------------------------- bias init (fallback path only)
__global__ void bias_init_kernel(const float* __restrict__ bias, float* __restrict__ out)
{
    int i = blockIdx.x * 256 + threadIdx.x;     // 16384 total
    out[i] = bias[i & (OUT_DIM - 1)];
}

// ------------- kernel A: feature expand -> bf16, MFMA-A-fragment packed
// layout: unit u = (chunk*16 + koctet)*32 + b holds f[b][chunk*128+koctet*8 .. +7]
__global__ __launch_bounds__(256)
void feat_pack_kernel(const float* __restrict__ x, int4* __restrict__ fp)
{
    const int chunk = blockIdx.x;               // 0..4107
    const int tid   = threadIdx.x;

    #pragma unroll
    for (int i = 0; i < 2; ++i) {
        const int unit = tid + i * 256;         // 0..511
        const int kb   = unit >> 5;             // k-octet 0..15
        const int b    = unit & 31;
        const int k0   = chunk * 128 + kb * 8;
        const float* xb = x + b * IN_DIM;

        float v[8];
        if (chunk < 8) {                        // linear features (k < 1024)
            #pragma unroll
            for (int e = 0; e < 8; ++e) v[e] = xb[k0 + e];
        } else {                                // quadratic: walk (r,c) from one sqrt
            int t = k0 - IN_DIM;
            float disc = 4198401.0f - 8.0f * (float)t;   // 2049^2 - 8t, exact in fp32
            int r = (int)((2049.0f - sqrtf(disc)) * 0.5f);
            int off = r * IN_DIM - ((r * (r - 1)) >> 1);
            if (t < off) { --r; off = r * IN_DIM - ((r * (r - 1)) >> 1); }
            else if (t >= off + (IN_DIM - r)) { off += IN_DIM - r; ++r; }
            int c_ = r + (t - off);
            #pragma unroll
            for (int e = 0; e < 8; ++e) {
                v[e] = xb[r] * xb[c_];
                if (c_ == IN_DIM - 1) { ++r; c_ = r; } else { ++c_; }
            }
        }
        int4 pk;
        pk.x = (int)pk2(v[0], v[1]);
        pk.y = (int)pk2(v[2], v[3]);
        pk.z = (int)pk2(v[4], v[5]);
        pk.w = (int)pk2(v[6], v[7]);
        fp[(size_t)chunk * 512 + unit] = pk;
    }
}

// ------------- kernel B: MFMA GEMM, split-K partials (no atomics).
// Wave = one o-16-tile x one k-segment; block = 4 waves sharing f-LDS.
// A (f) bf16 from packed LDS; B (W) fp32 global->reg->cvt; C = 2x f32x4/lane.
__global__ __launch_bounds__(256, 4)            // cap 128 VGPR, 4 blocks/CU
void qgemm_mfma_kernel(const int4* __restrict__ fp,
                       const float* __restrict__ W,
                       float* __restrict__ partial)
{
    __shared__ int4 fbuf[3][512];                // 3 x 8 KB

    const int tid  = threadIdx.x;
    const int lane = tid & 63;
    const int wv_  = tid >> 6;                   // 0..3
    const int lrow = lane & 15;                  // A row / B col within tile
    const int lkb  = lane >> 4;                  // k-octet group 0..3

    const int og = blockIdx.x >> 7;              // 0..7
    const int kg = blockIdx.x & (KGN - 1);       // 0..127 (bid%8 = kg%8: co-XCD f sharing)

    const int o_base = og * 64 + wv_ * 16;
    const float* wlane = W + (size_t)(o_base + lrow) * K_TOTAL;
    const char*  fpB   = (const char*)fp + (size_t)lane * 16;

    f32x4 acc0 = {0.f, 0.f, 0.f, 0.f};
    f32x4 acc1 = {0.f, 0.f, 0.f, 0.f};
    float4 wc[8], wn[8];

    #define WLOADR(dst, cc)                                                     \
    do {                                                                        \
        const float* wp_ = wlane + (size_t)(cc) * 128 + lkb * 8;                \
        _Pragma("unroll")                                                       \
        for (int q_ = 0; q_ < 4; ++q_) {                                        \
            dst[2*q_]   = *(const float4*)(wp_ + q_ * 32);                      \
            dst[2*q_+1] = *(const float4*)(wp_ + q_ * 32 + 4);                  \
        }                                                                       \
    } while (0)

    #define STAGEF(s, cc)                                                       \
    do {                                                                        \
        const char* gp_ = fpB + (size_t)(cc) * 8192;                            \
        GLD16(gp_ + wv_ * 1024,        (char*)&fbuf[s][0] + wv_ * 1024);        \
        GLD16(gp_ + 4096 + wv_ * 1024, (char*)&fbuf[s][0] + 4096 + wv_ * 1024); \
    } while (0)

    #define COMPUTE(cbuf)                                                       \
    do {                                                                        \
        const int4* bp_ = &fbuf[cbuf][0];                                       \
        _Pragma("unroll")                                                       \
        for (int q_ = 0; q_ < 4; ++q_) {                                        \
            int4 tw_;                                                           \
            tw_.x = (int)pk2(wc[2*q_].x,   wc[2*q_].y);                         \
            tw_.y = (int)pk2(wc[2*q_].z,   wc[2*q_].w);                         \
            tw_.z = (int)pk2(wc[2*q_+1].x, wc[2*q_+1].y);                       \
            tw_.w = (int)pk2(wc[2*q_+1].z, wc[2*q_+1].w);                       \
            const bfrag bw_ = __builtin_bit_cast(bfrag, tw_);                   \
            const int ub_ = (q_ * 4 + lkb) * 32 + lrow;                         \
            const bfrag a0_ = __builtin_bit_cast(bfrag, bp_[ub_]);              \
            const bfrag a1_ = __builtin_bit_cast(bfrag, bp_[ub_ + 16]);         \
            acc0 = __builtin_amdgcn_mfma_f32_16x16x32_bf16(a0_, bw_, acc0, 0, 0, 0); \
            acc1 = __builtin_amdgcn_mfma_f32_16x16x32_bf16(a1_, bw_, acc1, 0, 0, 0); \
        }                                                                       \
    } while (0)

    int c = kg;
    STAGEF(0, c);                                // f(c)
    WLOADR(wn, c);                               // W(c)
    STAGEF(1, c + KGN);                          // f(c+KGN): 12 vmem in flight

    int cb = 0, sb = 2;
    for (; c < NCH; c += KGN) {
        asm volatile("s_waitcnt vmcnt(2)" ::: "memory");   // f(c), W(c) landed
        __builtin_amdgcn_s_barrier();            // all waves' f(c) in LDS; buf sb free
        #pragma unroll
        for (int j = 0; j < 8; ++j) wc[j] = wn[j];
        const int cw = (c + KGN     < NCH) ? c + KGN     : c;
        const int cf = (c + 2 * KGN < NCH) ? c + 2 * KGN : c;
        WLOADR(wn, cw);
        STAGEF(sb, cf);
        COMPUTE(cb);
        cb = (cb == 2) ? 0 : cb + 1;
        sb = (sb == 2) ? 0 : sb + 1;
    }
    asm volatile("s_waitcnt vmcnt(0)" ::: "memory");       // drain DMA before exit

    #undef COMPUTE
    #undef STAGEF
    #undef WLOADR

    // C layout: C[b = (lane>>4)*4 + reg][o = lane&15]; plain stores to partial[kg]
    float* pb = partial + (size_t)kg * (B_SZ * OUT_DIM) + o_base + lrow;
    const int r0 = lkb * 4;
    #pragma unroll
    for (int r = 0; r < 4; ++r) {
        pb[(size_t)(r0 + r) * OUT_DIM]      = acc0[r];
        pb[(size_t)(16 + r0 + r) * OUT_DIM] = acc1[r];
    }
}

// ------------- kernel C: reduce 128 partials + bias -> out
__global__ __launch_bounds__(256)
void reduce_kernel(const float* __restrict__ partial,
                   const float* __restrict__ bias,
                   float* __restrict__ out)
{
    const int idx = blockIdx.x * 256 + threadIdx.x;   // 0..16383
    float s = bias[idx & (OUT_DIM - 1)];
    const float* p = partial + idx;
    #pragma unroll 8
    for (int kg = 0; kg < KGN; ++kg)
        s += p[(size_t)kg * (B_SZ * OUT_DIM)];
    out[idx] = s;
}

// ------------------------------------------------- fallback (proven v2 path)
__global__ __launch_bounds__(512, 2)
void qgemm_fallback_kernel(const float* __restrict__ x,
                           const float* __restrict__ W,
                           float* __restrict__ out)
{
    __shared__ float xt[B_SZ][512];

    const int tid  = threadIdx.x;
    const int lane = tid & 63;
    const int wave = tid >> 6;
    const int bgrp = wave & 3;
    const int ogrp = wave >> 2;

    const int og  = blockIdx.x & 31;
    const int kgf = blockIdx.x >> 5;

    const int o_base = og * 16 + ogrp * 8;
    const int b_base = bgrp * 8;

    float acc[8][8];
    #pragma unroll
    for (int i = 0; i < 8; ++i)
        #pragma unroll
        for (int o = 0; o < 8; ++o) acc[i][o] = 0.f;

    const int nch = (K_TOTAL + 511) / 512;
    for (int chunk = kgf; chunk < nch; chunk += 16) {
        const int k = chunk * 512 + tid;
        __syncthreads();
        if (k < IN_DIM) {
            #pragma unroll
            for (int b = 0; b < B_SZ; ++b)
                xt[b][tid] = x[b * IN_DIM + k];
        } else {
            const int t = k - IN_DIM;
            double disc = 4198401.0 - 8.0 * (double)t;
            int r = (int)((2049.0 - sqrt(disc)) * 0.5);
            int off = r * IN_DIM - ((r * (r - 1)) >> 1);
            if (t < off) { --r; off = r * IN_DIM - ((r * (r - 1)) >> 1); }
            else if (t >= off + (IN_DIM - r)) { off += IN_DIM - r; ++r; }
            const int ccol = r + (t - off);
            #pragma unroll
            for (int b = 0; b < B_SZ; ++b)
                xt[b][tid] = x[b * IN_DIM + r] * x[b * IN_DIM + ccol];
        }
        __syncthreads();

        const float* wrow = W + (size_t)o_base * K_TOTAL + (size_t)chunk * 512;
        #pragma unroll
        for (int pass = 0; pass < 2; ++pass) {
            const int kk = pass * 256 + lane * 4;
            float4 wv[8];
            #pragma unroll
            for (int o = 0; o < 8; ++o)
                wv[o] = *(const float4*)(wrow + (size_t)o * K_TOTAL + kk);
            float4 xv[8];
            #pragma unroll
            for (int i = 0; i < 8; ++i)
                xv[i] = *(const float4*)&xt[b_base + i][kk];
            #pragma unroll
            for (int o = 0; o < 8; ++o)
                #pragma unroll
                for (int i = 0; i < 8; ++i)
                    acc[i][o] += xv[i].x * wv[o].x + xv[i].y * wv[o].y
                               + xv[i].z * wv[o].z + xv[i].w * wv[o].w;
        }
    }

    #pragma unroll
    for (int i = 0; i < 8; ++i)
        #pragma unroll
        for (int o = 0; o < 8; ++o) {
            float v = acc[i][o];
            #pragma unroll
            for (int m = 1; m < 64; m <<= 1)
                v += __shfl_xor(v, m);
            acc[i][o] = v;
        }

    if (lane == 0) {
        #pragma unroll
        for (int i = 0; i < 8; ++i)
            #pragma unroll
            for (int o = 0; o < 8; ++o)
                atomicAdd(&out[(b_base + i) * OUT_DIM + o_base + o], acc[i][o]);
    }
}

extern "C" void kernel_launch(void* const* d_in, const int* in_sizes, int n_in,
                              void* d_out, int out_size, void* d_ws, size_t ws_size,
                              hipStream_t stream)
{
    const float* x    = (const float*)d_in[0];   // [32,1024] fp32
    const float* W    = (const float*)d_in[1];   // [512, 525824] fp32
    const float* bias = (const float*)d_in[2];   // [512] fp32
    float* out = (float*)d_out;                  // [32,512] fp32

    if (ws_size >= NEED_WS) {
        int4*  fpk  = (int4*)d_ws;
        float* part = (float*)((char*)d_ws + F_BYTES);
        hipLaunchKernelGGL(feat_pack_kernel, dim3(NCH), dim3(256), 0, stream, x, fpk);
        hipLaunchKernelGGL(qgemm_mfma_kernel, dim3(8 * KGN), dim3(256), 0, stream,
                           fpk, W, part);
        hipLaunchKernelGGL(reduce_kernel, dim3(64), dim3(256), 0, stream,
                           part, bias, out);
    } else {
        hipLaunchKernelGGL(bias_init_kernel, dim3(64), dim3(256), 0, stream, bias, out);
        hipLaunchKernelGGL(qgemm_fallback_kernel, dim3(512), dim3(512), 0, stream,
                           x, W, out);
    }
}

// Round 14
// 282.161 us; speedup vs baseline: 1.1092x; 1.1092x over previous
//
#include <hip/hip_runtime.h>
#include <hip/hip_bf16.h>

#define B_SZ     32
#define IN_DIM   1024
#define K_TOTAL  525824          // 1024 linear + 524800 triu = 4108 * 128
#define OUT_DIM  512
#define NCH      4108            // 128-k chunks
#define NPAIR    2054            // 256-k pairs
#define KGN      128             // pair-group count (pair stride)
#define F_BYTES  ((size_t)NCH * 8192)            // 33,652,736 packed bf16 features
#define P_ELEMS  ((size_t)KGN * B_SZ * OUT_DIM)  // 128 * 16384 partials
#define NEED_WS  (F_BYTES + P_ELEMS * 4)

typedef __attribute__((ext_vector_type(8))) short bfrag;   // 8 bf16 = 4 VGPR
typedef __attribute__((ext_vector_type(4))) float f32x4;

// async global->LDS, 16B per lane; LDS dest = wave-uniform base + lane*16
#define GLD16(g, l) __builtin_amdgcn_global_load_lds(                      \
    (const __attribute__((address_space(1))) void*)(g),                    \
    (__attribute__((address_space(3))) void*)(l), 16, 0, 0)

// fp32 -> bf16 round-to-nearest-even (pure integer)
__device__ inline unsigned bf16r(float f)
{
    unsigned u = __builtin_bit_cast(unsigned, f);
    return (u + 0x7FFFu + ((u >> 16) & 1u)) >> 16;
}
__device__ inline unsigned pk2(float a, float b)
{
    return bf16r(a) | (bf16r(b) << 16);
}

// ---------------------------------------------------------------- bias init (fallback path only)
__global__ void bias_init_kernel(const float* __restrict__ bias, float* __restrict__ out)
{
    int i = blockIdx.x * 256 + threadIdx.x;     // 16384 total
    out[i] = bias[i & (OUT_DIM - 1)];
}

// ------------- kernel A: feature expand -> bf16, MFMA-A-fragment packed
// layout: unit u = (chunk*16 + koctet)*32 + b holds f[b][chunk*128+koctet*8 .. +7]
__global__ __launch_bounds__(256)
void feat_pack_kernel(const float* __restrict__ x, int4* __restrict__ fp)
{
    const int chunk = blockIdx.x;               // 0..4107
    const int tid   = threadIdx.x;

    #pragma unroll
    for (int i = 0; i < 2; ++i) {
        const int unit = tid + i * 256;         // 0..511
        const int kb   = unit >> 5;             // k-octet 0..15
        const int b    = unit & 31;
        const int k0   = chunk * 128 + kb * 8;
        const float* xb = x + b * IN_DIM;

        float v[8];
        if (chunk < 8) {                        // linear features (k < 1024)
            #pragma unroll
            for (int e = 0; e < 8; ++e) v[e] = xb[k0 + e];
        } else {                                // quadratic: walk (r,c) from one sqrt
            int t = k0 - IN_DIM;
            float disc = 4198401.0f - 8.0f * (float)t;   // 2049^2 - 8t, exact in fp32
            int r = (int)((2049.0f - sqrtf(disc)) * 0.5f);
            int off = r * IN_DIM - ((r * (r - 1)) >> 1);
            if (t < off) { --r; off = r * IN_DIM - ((r * (r - 1)) >> 1); }
            else if (t >= off + (IN_DIM - r)) { off += IN_DIM - r; ++r; }
            int c_ = r + (t - off);
            #pragma unroll
            for (int e = 0; e < 8; ++e) {
                v[e] = xb[r] * xb[c_];
                if (c_ == IN_DIM - 1) { ++r; c_ = r; } else { ++c_; }
            }
        }
        int4 pk;
        pk.x = (int)pk2(v[0], v[1]);
        pk.y = (int)pk2(v[2], v[3]);
        pk.z = (int)pk2(v[4], v[5]);
        pk.w = (int)pk2(v[6], v[7]);
        fp[(size_t)chunk * 512 + unit] = pk;
    }
}

// ------------- kernel B: MFMA GEMM, pair-chunk periods (1 KB W spans/row).
// Wave = one o-16-tile x one pair-segment; block = 4 waves sharing f-LDS.
// Per period: 2 consecutive 128-k chunks -> 16 W float4/lane (1 KB/row burst),
// cvt fp32->bf16 after the wait frees the prefetch set; 16 MFMA; split-K store.
__global__ __launch_bounds__(256, 2)            // cap 256 VGPR: spill-proof
void qgemm_mfma_kernel(const int4* __restrict__ fp,
                       const float* __restrict__ W,
                       float* __restrict__ partial)
{
    __shared__ int4 fbuf[3][1024];               // 3 x 16 KB (pair tiles)

    const int tid  = threadIdx.x;
    const int lane = tid & 63;
    const int wv_  = tid >> 6;                   // 0..3
    const int lrow = lane & 15;                  // A row / B col within tile
    const int lkb  = lane >> 4;                  // k-octet group 0..3

    const int og = blockIdx.x >> 7;              // 0..7
    const int kg = blockIdx.x & (KGN - 1);       // 0..127 (bid%8 = kg%8: co-XCD f sharing)

    const int o_base = og * 64 + wv_ * 16;
    const float* wlane = W + (size_t)(o_base + lrow) * K_TOTAL;
    const char*  fpB   = (const char*)fp + (size_t)lane * 16;

    f32x4 acc0 = {0.f, 0.f, 0.f, 0.f};
    f32x4 acc1 = {0.f, 0.f, 0.f, 0.f};
    float4 wn[16];                               // fp32 prefetch (pair)
    int4   wcb[8];                               // bf16 fragments (pair)

    // load W for pair pp: per row 1 KB contiguous, issued back-to-back
    #define WLOADP(pp)                                                          \
    do {                                                                        \
        const float* wp_ = wlane + (size_t)(pp) * 256 + lkb * 8;                \
        _Pragma("unroll")                                                       \
        for (int q_ = 0; q_ < 4; ++q_) {                                        \
            wn[2*q_]   = *(const float4*)(wp_ + q_ * 32);                       \
            wn[2*q_+1] = *(const float4*)(wp_ + q_ * 32 + 4);                   \
        }                                                                       \
        _Pragma("unroll")                                                       \
        for (int q_ = 0; q_ < 4; ++q_) {                                        \
            wn[8+2*q_]   = *(const float4*)(wp_ + 128 + q_ * 32);               \
            wn[8+2*q_+1] = *(const float4*)(wp_ + 128 + q_ * 32 + 4);           \
        }                                                                       \
    } while (0)

    // stage f pair pp (16 KB contiguous) into buffer s
    #define STAGEF(s, pp)                                                       \
    do {                                                                        \
        const char* gp_ = fpB + (size_t)(pp) * 16384 + wv_ * 4096;              \
        _Pragma("unroll")                                                       \
        for (int j_ = 0; j_ < 4; ++j_)                                          \
            GLD16(gp_ + j_ * 1024, (char*)&fbuf[s][0] + wv_ * 4096 + j_ * 1024);\
    } while (0)

    // convert the fp32 prefetch (current pair) into bf16 fragments
    #define CVTW()                                                              \
    do {                                                                        \
        _Pragma("unroll")                                                       \
        for (int e_ = 0; e_ < 8; ++e_) {                                        \
            int4 tw_;                                                           \
            tw_.x = (int)pk2(wn[2*e_].x,   wn[2*e_].y);                         \
            tw_.y = (int)pk2(wn[2*e_].z,   wn[2*e_].w);                         \
            tw_.z = (int)pk2(wn[2*e_+1].x, wn[2*e_+1].y);                       \
            tw_.w = (int)pk2(wn[2*e_+1].z, wn[2*e_+1].w);                       \
            wcb[e_] = tw_;                                                      \
        }                                                                       \
    } while (0)

    #define COMPUTE(cbuf)                                                       \
    do {                                                                        \
        const int4* bp_ = &fbuf[cbuf][0];                                       \
        _Pragma("unroll")                                                       \
        for (int s_ = 0; s_ < 2; ++s_)                                          \
            _Pragma("unroll")                                                   \
            for (int q_ = 0; q_ < 4; ++q_) {                                    \
                const bfrag bw_ = __builtin_bit_cast(bfrag, wcb[s_*4 + q_]);    \
                const int ub_ = s_ * 512 + (q_ * 4 + lkb) * 32 + lrow;          \
                const bfrag a0_ = __builtin_bit_cast(bfrag, bp_[ub_]);          \
                const bfrag a1_ = __builtin_bit_cast(bfrag, bp_[ub_ + 16]);     \
                acc0 = __builtin_amdgcn_mfma_f32_16x16x32_bf16(a0_, bw_, acc0, 0, 0, 0); \
                acc1 = __builtin_amdgcn_mfma_f32_16x16x32_bf16(a1_, bw_, acc1, 0, 0, 0); \
            }                                                                   \
    } while (0)

    const int n  = 16 + (kg < 6 ? 1 : 0);        // pairs owned: kg + t*128 < 2054
    int pc = kg;

    STAGEF(0, pc);                               // f(p0) x4
    WLOADP(pc);                                  // W(p0) x16
    STAGEF(1, pc + KGN);                         // f(p1) x4   -> 24 in flight

    int cb = 0, sb = 2;
    for (int t = 0; t < n; ++t) {
        asm volatile("s_waitcnt vmcnt(4)" ::: "memory");   // f(t),W(t) landed; f(t+1) may fly
        __builtin_amdgcn_s_barrier();            // all waves past COMPUTE(t-1)
        CVTW();                                  // wn -> wcb, frees wn
        const int pw = (t + 1 < n) ? pc + KGN     : pc;    // clamped re-reads are harmless
        const int pf = (t + 2 < n) ? pc + 2 * KGN : pw;
        WLOADP(pw);
        STAGEF(sb, pf);
        COMPUTE(cb);
        cb = (cb == 2) ? 0 : cb + 1;
        sb = (sb == 2) ? 0 : sb + 1;
        pc += KGN;
    }
    asm volatile("s_waitcnt vmcnt(0)" ::: "memory");       // drain DMA before exit

    #undef COMPUTE
    #undef CVTW
    #undef STAGEF
    #undef WLOADP

    // C layout: C[b = (lane>>4)*4 + reg][o = lane&15]; plain stores to partial[kg]
    float* pb = partial + (size_t)kg * (B_SZ * OUT_DIM) + o_base + lrow;
    const int r0 = lkb * 4;
    #pragma unroll
    for (int r = 0; r < 4; ++r) {
        pb[(size_t)(r0 + r) * OUT_DIM]      = acc0[r];
        pb[(size_t)(16 + r0 + r) * OUT_DIM] = acc1[r];
    }
}

// ------------- kernel C: reduce 128 partials + bias -> out
__global__ __launch_bounds__(256)
void reduce_kernel(const float* __restrict__ partial,
                   const float* __restrict__ bias,
                   float* __restrict__ out)
{
    const int idx = blockIdx.x * 256 + threadIdx.x;   // 0..16383
    float s = bias[idx & (OUT_DIM - 1)];
    const float* p = partial + idx;
    #pragma unroll 8
    for (int kg = 0; kg < KGN; ++kg)
        s += p[(size_t)kg * (B_SZ * OUT_DIM)];
    out[idx] = s;
}

// ------------------------------------------------- fallback (proven v2 path)
__global__ __launch_bounds__(512, 2)
void qgemm_fallback_kernel(const float* __restrict__ x,
                           const float* __restrict__ W,
                           float* __restrict__ out)
{
    __shared__ float xt[B_SZ][512];

    const int tid  = threadIdx.x;
    const int lane = tid & 63;
    const int wave = tid >> 6;
    const int bgrp = wave & 3;
    const int ogrp = wave >> 2;

    const int og  = blockIdx.x & 31;
    const int kgf = blockIdx.x >> 5;

    const int o_base = og * 16 + ogrp * 8;
    const int b_base = bgrp * 8;

    float acc[8][8];
    #pragma unroll
    for (int i = 0; i < 8; ++i)
        #pragma unroll
        for (int o = 0; o < 8; ++o) acc[i][o] = 0.f;

    const int nch = (K_TOTAL + 511) / 512;
    for (int chunk = kgf; chunk < nch; chunk += 16) {
        const int k = chunk * 512 + tid;
        __syncthreads();
        if (k < IN_DIM) {
            #pragma unroll
            for (int b = 0; b < B_SZ; ++b)
                xt[b][tid] = x[b * IN_DIM + k];
        } else {
            const int t = k - IN_DIM;
            double disc = 4198401.0 - 8.0 * (double)t;
            int r = (int)((2049.0 - sqrt(disc)) * 0.5);
            int off = r * IN_DIM - ((r * (r - 1)) >> 1);
            if (t < off) { --r; off = r * IN_DIM - ((r * (r - 1)) >> 1); }
            else if (t >= off + (IN_DIM - r)) { off += IN_DIM - r; ++r; }
            const int ccol = r + (t - off);
            #pragma unroll
            for (int b = 0; b < B_SZ; ++b)
                xt[b][tid] = x[b * IN_DIM + r] * x[b * IN_DIM + ccol];
        }
        __syncthreads();

        const float* wrow = W + (size_t)o_base * K_TOTAL + (size_t)chunk * 512;
        #pragma unroll
        for (int pass = 0; pass < 2; ++pass) {
            const int kk = pass * 256 + lane * 4;
            float4 wv[8];
            #pragma unroll
            for (int o = 0; o < 8; ++o)
                wv[o] = *(const float4*)(wrow + (size_t)o * K_TOTAL + kk);
            float4 xv[8];
            #pragma unroll
            for (int i = 0; i < 8; ++i)
                xv[i] = *(const float4*)&xt[b_base + i][kk];
            #pragma unroll
            for (int o = 0; o < 8; ++o)
                #pragma unroll
                for (int i = 0; i < 8; ++i)
                    acc[i][o] += xv[i].x * wv[o].x + xv[i].y * wv[o].y
                               + xv[i].z * wv[o].z + xv[i].w * wv[o].w;
        }
    }

    #pragma unroll
    for (int i = 0; i < 8; ++i)
        #pragma unroll
        for (int o = 0; o < 8; ++o) {
            float v = acc[i][o];
            #pragma unroll
            for (int m = 1; m < 64; m <<= 1)
                v += __shfl_xor(v, m);
            acc[i][o] = v;
        }

    if (lane == 0) {
        #pragma unroll
        for (int i = 0; i < 8; ++i)
            #pragma unroll
            for (int o = 0; o < 8; ++o)
                atomicAdd(&out[(b_base + i) * OUT_DIM + o_base + o], acc[i][o]);
    }
}

extern "C" void kernel_launch(void* const* d_in, const int* in_sizes, int n_in,
                              void* d_out, int out_size, void* d_ws, size_t ws_size,
                              hipStream_t stream)
{
    const float* x    = (const float*)d_in[0];   // [32,1024] fp32
    const float* W    = (const float*)d_in[1];   // [512, 525824] fp32
    const float* bias = (const float*)d_in[2];   // [512] fp32
    float* out = (float*)d_out;                  // [32,512] fp32

    if (ws_size >= NEED_WS) {
        int4*  fpk  = (int4*)d_ws;
        float* part = (float*)((char*)d_ws + F_BYTES);
        hipLaunchKernelGGL(feat_pack_kernel, dim3(NCH), dim3(256), 0, stream, x, fpk);
        hipLaunchKernelGGL(qgemm_mfma_kernel, dim3(8 * KGN), dim3(256), 0, stream,
                           fpk, W, part);
        hipLaunchKernelGGL(reduce_kernel, dim3(64), dim3(256), 0, stream,
                           part, bias, out);
    } else {
        hipLaunchKernelGGL(bias_init_kernel, dim3(64), dim3(256), 0, stream, bias, out);
        hipLaunchKernelGGL(qgemm_fallback_kernel, dim3(512), dim3(512), 0, stream,
                           x, W, out);
    }
}